// Round 3
// baseline (756.225 us; speedup 1.0000x reference)
//
#include <hip/hip_runtime.h>
#include <math.h>

#define BB 32
#define DD 256
#define KK 2048
#define HW 1024
#define CHW (DD*HW)
#define NN (BB*HW)         // 32768 rows
#define BETA 0.25f

#define BLK_R 64           // rows per block (screen)
#define BLK_K 256          // codes per k-tile
#define DC 32              // d-chunk
#define PITCH 36           // LDS row pitch (floats)
#define NCAND 4            // refine candidates per row
#define RROWS 32           // rows per refine block

// ---- kernel C: C[k] = np-pairwise-fp32 sum of e_d^2 (bitwise numpy order) ----
__global__ __launch_bounds__(256) void k_c(const float* __restrict__ E,
                                           float* __restrict__ C) {
    int k = blockIdx.x * 256 + threadIdx.x;
    const float* e = E + (size_t)k * DD;
    float res;
    {
#pragma clang fp contract(off)
        float r0[8], r1[8];
        #pragma unroll
        for (int j = 0; j < 8; ++j) { float t = e[j];       r0[j] = t * t; }
        #pragma unroll
        for (int j = 0; j < 8; ++j) { float t = e[128 + j]; r1[j] = t * t; }
        for (int i = 8; i < 128; i += 8) {
            #pragma unroll
            for (int j = 0; j < 8; ++j) { float t = e[i + j];       r0[j] += t * t; }
            #pragma unroll
            for (int j = 0; j < 8; ++j) { float t = e[128 + i + j]; r1[j] += t * t; }
        }
        float lo = ((r0[0] + r0[1]) + (r0[2] + r0[3])) + ((r0[4] + r0[5]) + (r0[6] + r0[7]));
        float hi = ((r1[0] + r1[1]) + (r1[2] + r1[3])) + ((r1[4] + r1[5]) + (r1[6] + r1[7]));
        res = lo + hi;
    }
    C[k] = res;
}

// ------- screen: fused distance GEMM + per-row top-4 candidates -------
// approx score(n,k) = C[k] - 2 * x_n . e_k   (|x|^2 omitted: row-constant)
__global__ __launch_bounds__(256, 2) void k_dist(const float* __restrict__ X,
                                                 const float* __restrict__ E,
                                                 const float* __restrict__ C,
                                                 int* __restrict__ ck) {
    __shared__ float Xs[BLK_R][PITCH];
    __shared__ float Es[BLK_K][PITCH];

    const int tid = threadIdx.x;
    const int tx = tid & 31;
    const int ty = tid >> 5;
    const int nb = blockIdx.x * BLK_R;
    const int b  = nb >> 10;
    const int hw = nb & 1023;
    const float* xbase = X + (size_t)b * CHW + hw;

    float s1[8], s2[8];
    int   k1[8], k2[8];
    #pragma unroll
    for (int i = 0; i < 8; ++i) {
        s1[i] = INFINITY; s2[i] = INFINITY; k1[i] = 0x7fffffff; k2[i] = 0x7fffffff;
    }

    for (int kt = 0; kt < KK; kt += BLK_K) {
        float acc[8][8];
        #pragma unroll
        for (int r = 0; r < 8; ++r)
            #pragma unroll
            for (int c = 0; c < 8; ++c) acc[r][c] = 0.0f;

        for (int dt = 0; dt < DD; dt += DC) {
            __syncthreads();
            #pragma unroll
            for (int i = 0; i < 2; ++i) {
                int idx = tid + i * 256;
                int dd  = idx >> 4;
                int nn  = (idx & 15) << 2;
                float4 v = *reinterpret_cast<const float4*>(
                    xbase + (size_t)(dt + dd) * HW + nn);
                Xs[nn + 0][dd] = v.x;
                Xs[nn + 1][dd] = v.y;
                Xs[nn + 2][dd] = v.z;
                Xs[nn + 3][dd] = v.w;
            }
            const float* ebase = E + (size_t)kt * DD + dt;
            #pragma unroll
            for (int i = 0; i < 8; ++i) {
                int idx = tid + i * 256;
                int kk  = idx >> 3;
                int dd  = (idx & 7) << 2;
                float4 v = *reinterpret_cast<const float4*>(
                    ebase + (size_t)kk * DD + dd);
                *reinterpret_cast<float4*>(&Es[kk][dd]) = v;
            }
            __syncthreads();
            #pragma unroll
            for (int dd = 0; dd < DC; dd += 4) {
                float4 xf[8], ef[8];
                #pragma unroll
                for (int r = 0; r < 8; ++r)
                    xf[r] = *reinterpret_cast<const float4*>(&Xs[ty * 8 + r][dd]);
                #pragma unroll
                for (int c = 0; c < 8; ++c)
                    ef[c] = *reinterpret_cast<const float4*>(&Es[c * 32 + tx][dd]);
                #pragma unroll
                for (int r = 0; r < 8; ++r)
                    #pragma unroll
                    for (int c = 0; c < 8; ++c) {
                        acc[r][c] += xf[r].x * ef[c].x;
                        acc[r][c] += xf[r].y * ef[c].y;
                        acc[r][c] += xf[r].z * ef[c].z;
                        acc[r][c] += xf[r].w * ef[c].w;
                    }
            }
        }
        #pragma unroll
        for (int c = 0; c < 8; ++c) {
            int k = kt + c * 32 + tx;
            float e2 = C[k];
            #pragma unroll
            for (int r = 0; r < 8; ++r) {
                float s = e2 - 2.0f * acc[r][c];
                if (s < s1[r]) {
                    s2[r] = s1[r]; k2[r] = k1[r];
                    s1[r] = s;     k1[r] = k;
                } else if (s < s2[r]) {
                    s2[r] = s; k2[r] = k;
                }
            }
        }
    }

    // ---- pool per-thread top-2, then per-row top-4 ----
    __syncthreads();
    float* sA = &Es[0][0];
    float* sB = sA + 2048;
    int*   kA = reinterpret_cast<int*>(sA + 4096);
    int*   kB = reinterpret_cast<int*>(sA + 6144);
    #pragma unroll
    for (int r = 0; r < 8; ++r) {
        int slot = (ty * 8 + r) * 32 + tx;
        sA[slot] = s1[r]; kA[slot] = k1[r];
        sB[slot] = s2[r]; kB[slot] = k2[r];
    }
    __syncthreads();
    if (tid < BLK_R) {
        float bs[NCAND]; int bk[NCAND];
        #pragma unroll
        for (int c = 0; c < NCAND; ++c) { bs[c] = INFINITY; bk[c] = 0x7fffffff; }
        for (int j = 0; j < 32; ++j) {
            #pragma unroll
            for (int h = 0; h < 2; ++h) {
                float s = h ? sB[tid * 32 + j] : sA[tid * 32 + j];
                int   k = h ? kB[tid * 32 + j] : kA[tid * 32 + j];
                #pragma unroll
                for (int c = 0; c < NCAND; ++c) {
                    if (s < bs[c] || (s == bs[c] && k < bk[c])) {
                        for (int q = NCAND - 1; q > c; --q) {
                            bs[q] = bs[q - 1]; bk[q] = bk[q - 1];
                        }
                        bs[c] = s; bk[c] = k;
                        break;
                    }
                }
            }
        }
        #pragma unroll
        for (int c = 0; c < NCAND; ++c) ck[(nb + tid) * NCAND + c] = bk[c];
    }
}

// ------- refine: bitwise numpy-fp32 rescore of the 4 candidates per row -------
// dist = fl32( fl32( A - fl32(2*M) ) + C[k] ), A = np-pairwise |x|^2,
// M = fp32(dot(x,e)) (f64-accumulated proxy). Ties -> lowest k (np first index).
__global__ __launch_bounds__(256) void k_refine(const float* __restrict__ X,
                                                const float* __restrict__ E,
                                                const float* __restrict__ C,
                                                const int* __restrict__ ck,
                                                float* __restrict__ idx_out_f,
                                                int* __restrict__ ind) {
    __shared__ float Xl[RROWS][DD + 1];
    const int tid = threadIdx.x;
    const int n0 = blockIdx.x * RROWS;
    const int b  = n0 >> 10;
    const int hw0 = n0 & 1023;
    const float* xbase = X + (size_t)b * CHW + hw0;
    #pragma unroll
    for (int it = 0; it < RROWS; ++it) {
        int idx = tid + it * 256;          // 0..8191
        int d = idx >> 5;                  // 0..255
        int r = idx & 31;                  // 0..31
        Xl[r][d] = xbase[(size_t)d * HW + r];
    }
    __syncthreads();
    if (tid < RROWS) {
        const int r = tid;
        const int n = n0 + r;
        float A;
        {
#pragma clang fp contract(off)
            float r0[8], r1[8];
            #pragma unroll
            for (int j = 0; j < 8; ++j) { float t = Xl[r][j];       r0[j] = t * t; }
            #pragma unroll
            for (int j = 0; j < 8; ++j) { float t = Xl[r][128 + j]; r1[j] = t * t; }
            for (int i = 8; i < 128; i += 8) {
                #pragma unroll
                for (int j = 0; j < 8; ++j) { float t = Xl[r][i + j];       r0[j] += t * t; }
                #pragma unroll
                for (int j = 0; j < 8; ++j) { float t = Xl[r][128 + i + j]; r1[j] += t * t; }
            }
            float lo = ((r0[0] + r0[1]) + (r0[2] + r0[3])) + ((r0[4] + r0[5]) + (r0[6] + r0[7]));
            float hi = ((r1[0] + r1[1]) + (r1[2] + r1[3])) + ((r1[4] + r1[5]) + (r1[6] + r1[7]));
            A = lo + hi;
        }
        float bd = INFINITY; int bk = 0x7fffffff;
        for (int c = 0; c < NCAND; ++c) {
            int k = ck[n * NCAND + c];
            const float* e = E + (size_t)k * DD;
            double m = 0.0;
            for (int d = 0; d < DD; ++d)
                m += (double)Xl[r][d] * (double)e[d];
            float dist;
            {
#pragma clang fp contract(off)
                float M  = (float)m;
                float Bt = 2.0f * M;
                float T1 = A - Bt;
                dist = T1 + C[k];
            }
            if (dist < bd || (dist == bd && k < bk)) { bd = dist; bk = k; }
        }
        ind[n] = bk;
        idx_out_f[n] = (float)bk;
    }
}

// ------- output: out = x + BETA*(E[ind] - x), NCHW, float4 over w -------
__global__ __launch_bounds__(256) void k_out(const float* __restrict__ X,
                                             const float* __restrict__ E,
                                             const int* __restrict__ ind,
                                             float* __restrict__ out) {
    int g  = blockIdx.x * 256 + threadIdx.x;
    int e0 = g << 2;
    int hw = e0 & 1023;
    int d  = (e0 >> 10) & 255;
    int b  = e0 >> 18;
    int n0 = (b << 10) | hw;

    float4 x = *reinterpret_cast<const float4*>(X + e0);
    int4  iv = *reinterpret_cast<const int4*>(ind + n0);
    float q0 = E[(size_t)iv.x * DD + d];
    float q1 = E[(size_t)iv.y * DD + d];
    float q2 = E[(size_t)iv.z * DD + d];
    float q3 = E[(size_t)iv.w * DD + d];
    float4 r;
    r.x = x.x + BETA * (q0 - x.x);
    r.y = x.y + BETA * (q1 - x.y);
    r.z = x.z + BETA * (q2 - x.z);
    r.w = x.w + BETA * (q3 - x.w);
    *reinterpret_cast<float4*>(out + e0) = r;
}

extern "C" void kernel_launch(void* const* d_in, const int* in_sizes, int n_in,
                              void* d_out, int out_size, void* d_ws, size_t ws_size,
                              hipStream_t stream) {
    const float* lat = (const float*)d_in[0];      // (32,256,32,32) fp32
    const float* emb = (const float*)d_in[1];      // (2048,256) fp32
    float* out   = (float*)d_out;                  // 8388608 floats
    float* idx_f = out + (size_t)BB * DD * HW;     // 32768 floats (indices)

    float* Cbuf = (float*)d_ws;                                   // 2048 f
    int*   ind  = (int*)((char*)d_ws + 2048 * sizeof(float));     // 32768 i
    int*   ck   = ind + NN;                                       // 4*32768 i

    k_c     <<<KK / 256, 256, 0, stream>>>(emb, Cbuf);
    k_dist  <<<NN / BLK_R, 256, 0, stream>>>(lat, emb, Cbuf, ck);
    k_refine<<<NN / RROWS, 256, 0, stream>>>(lat, emb, Cbuf, ck, idx_f, ind);
    k_out   <<<(BB * DD * HW) / 4 / 256, 256, 0, stream>>>(lat, emb, ind, out);
}

// Round 5
// 186.491 us; speedup vs baseline: 4.0550x; 4.0550x over previous
//
#include <hip/hip_runtime.h>
#include <math.h>

#define BB 32
#define DD 256
#define KK 2048
#define HW 1024
#define CHW (DD*HW)
#define NN (BB*HW)         // 32768 rows
#define BETA 0.25f
#define NCAND 8
#define RROWS 32
#define BIAS 0.125f

typedef __attribute__((ext_vector_type(8))) short short8v;   // 8 bf16 (4 VGPR)
typedef __attribute__((ext_vector_type(4))) float f32x4;

typedef const __attribute__((address_space(1))) void gv_t;
typedef __attribute__((address_space(3))) void lv_t;

__device__ __forceinline__ void gl_lds16(const void* g, void* l) {
    // dest = wave-uniform base (+ lane*16 by HW); src = per-lane global addr
    __builtin_amdgcn_global_load_lds((gv_t*)g, (lv_t*)l, 16, 0, 0);
}

__device__ __forceinline__ unsigned bfr(float f) {           // fp32 -> bf16 RNE
    unsigned u = __float_as_uint(f);
    return (u + 0x7FFFu + ((u >> 16) & 1u)) >> 16;
}
__device__ __forceinline__ unsigned bfpack(float lo, float hi) {
    return bfr(lo) | (bfr(hi) << 16);
}

// ---- Cref[k] = np-pairwise-fp32 sum e^2 (bitwise numpy order); Ckey = +BIAS ----
__global__ __launch_bounds__(256) void k_c(const float* __restrict__ E,
                                           float* __restrict__ Cref,
                                           float* __restrict__ Ckey) {
    int k = blockIdx.x * 256 + threadIdx.x;
    const float* e = E + (size_t)k * DD;
    float res;
    {
#pragma clang fp contract(off)
        float r0[8], r1[8];
        #pragma unroll
        for (int j = 0; j < 8; ++j) { float t = e[j];       r0[j] = t * t; }
        #pragma unroll
        for (int j = 0; j < 8; ++j) { float t = e[128 + j]; r1[j] = t * t; }
        for (int i = 8; i < 128; i += 8) {
            #pragma unroll
            for (int j = 0; j < 8; ++j) { float t = e[i + j];       r0[j] += t * t; }
            #pragma unroll
            for (int j = 0; j < 8; ++j) { float t = e[128 + i + j]; r1[j] += t * t; }
        }
        float lo = ((r0[0]+r0[1])+(r0[2]+r0[3]))+((r0[4]+r0[5])+(r0[6]+r0[7]));
        float hi = ((r1[0]+r1[1])+(r1[2]+r1[3]))+((r1[4]+r1[5])+(r1[6]+r1[7]));
        res = lo + hi;
    }
    Cref[k] = res;
    Ckey[k] = res + BIAS;
}

// ---- E fp32 -> bf16, tiled: unit u = ((kt*8+c)*4+kc)*256+code ; 65536 units ----
__global__ __launch_bounds__(256) void k_ebf(const float* __restrict__ E,
                                             uint4* __restrict__ EbfT) {
    int u = blockIdx.x * 256 + threadIdx.x;          // 0..65535
    int code = u & 255, kc = (u >> 8) & 3, c = (u >> 10) & 7, kt = u >> 13;
    const float* s = E + ((size_t)(kt * 256 + code) * 256 + c * 32 + kc * 8);
    float4 f0 = *reinterpret_cast<const float4*>(s);
    float4 f1 = *reinterpret_cast<const float4*>(s + 4);
    uint4 o;
    o.x = bfpack(f0.x, f0.y); o.y = bfpack(f0.z, f0.w);
    o.z = bfpack(f1.x, f1.y); o.w = bfpack(f1.z, f1.w);
    EbfT[u] = o;
}

// ---- X NCHW fp32 -> [n][d] bf16, tiled: unit = rb*2048 + S*256 + kc*64 + row ----
__global__ __launch_bounds__(256) void k_xbf(const float* __restrict__ X,
                                             uint4* __restrict__ XbfT) {
    __shared__ float Tr[64][65];
    int tid = threadIdx.x;
    int bid = blockIdx.x;                  // 2048 blocks
    int b = bid >> 6, r = bid & 63;
    int hw0 = (r & 15) * 64, d0 = (r >> 4) * 64;
    const float* xb = X + (size_t)b * CHW + (size_t)d0 * HW + hw0;
    for (int j = 0; j < 16; ++j) {
        int idx = tid + j * 256;
        int d_l = idx >> 6, hw_l = idx & 63;
        Tr[hw_l][d_l] = xb[(size_t)d_l * HW + hw_l];   // coalesced 64-float rows
    }
    __syncthreads();
    int rb = b * 16 + (r & 15);
    for (int j = 0; j < 2; ++j) {
        int u = tid + j * 256;             // 0..511
        int hw_l = u & 63, c8 = u >> 6;    // 0..7
        int d = d0 + c8 * 8;
        const float* t = &Tr[hw_l][c8 * 8];
        uint4 o;
        o.x = bfpack(t[0], t[1]); o.y = bfpack(t[2], t[3]);
        o.z = bfpack(t[4], t[5]); o.w = bfpack(t[6], t[7]);
        int unit = rb * 2048 + (d >> 5) * 256 + ((d >> 3) & 3) * 64 + hw_l;
        XbfT[unit] = o;                    // coalesced 16B writes
    }
}

// ---- MFMA screen: per-row top-8 candidate codes via packed sortable keys ----
__global__ __launch_bounds__(256, 2) void k_screen(
        const uint4* __restrict__ XbfT, const uint4* __restrict__ EbfT,
        const float* __restrict__ Ckey, int* __restrict__ ck)
{
    __shared__ __align__(1024) char lds[65536];
    char* XsB = lds;              // 32 KB: units [S 8][kc 4][row 64] x 16B
    char* EsB = lds + 32768;      // 2 x 16 KB: units [kc 4][code 256] x 16B

    const int tid = threadIdx.x;
    const int w = tid >> 6;
    const int lane = tid & 63;
    const int lid = lane & 15;
    const int kc = lane >> 4;
    const int nb = blockIdx.x * 64;

    // stage Xs once (linear DMA from tiled global)
    #pragma unroll
    for (int i = 0; i < 8; ++i)
        gl_lds16(XbfT + ((size_t)blockIdx.x * 2048 + w * 512 + i * 64 + lane),
                 XsB + (w * 512 + i * 64) * 16);
    // stage E chunk (kt=0,c=0) -> buf0
    #pragma unroll
    for (int i = 0; i < 4; ++i)
        gl_lds16(EbfT + (w * 256 + i * 64 + lane), EsB + (w * 256 + i * 64) * 16);
    asm volatile("s_waitcnt vmcnt(0)" ::: "memory");
    __syncthreads();

    const f32x4 zero4 = {0.0f, 0.0f, 0.0f, 0.0f};
    f32x4 acc[4][4];
    unsigned t1[4][4], t2[4][4];
    #pragma unroll
    for (int i = 0; i < 4; ++i)
        #pragma unroll
        for (int j = 0; j < 4; ++j) {
            acc[i][j] = zero4; t1[i][j] = 0xFFFFFFFFu; t2[i][j] = 0xFFFFFFFFu;
        }

    int p = 0;
    for (int kt = 0; kt < 8; ++kt) {
        for (int c = 0; c < 8; ++c) {
            int nkt = kt, nc = c + 1;
            if (nc == 8) { nc = 0; ++nkt; }
            if (nkt < 8) {                       // prefetch next chunk -> buf p^1
                const uint4* src = EbfT + ((size_t)(nkt * 8 + nc) * 1024 + w * 256);
                char* dst = EsB + (p ^ 1) * 16384 + (w * 256) * 16;
                #pragma unroll
                for (int i = 0; i < 4; ++i)
                    gl_lds16(src + i * 64 + lane, dst + i * 1024);
            }
            const short8v* Xv = reinterpret_cast<const short8v*>(XsB);
            const short8v* Ev = reinterpret_cast<const short8v*>(EsB + p * 16384);
            short8v a[4], b[4];
            #pragma unroll
            for (int rt = 0; rt < 4; ++rt)
                a[rt] = Xv[(c * 4 + kc) * 64 + rt * 16 + lid];
            #pragma unroll
            for (int ct = 0; ct < 4; ++ct)
                b[ct] = Ev[kc * 256 + w * 64 + ct * 16 + lid];
            #pragma unroll
            for (int rt = 0; rt < 4; ++rt)
                #pragma unroll
                for (int ct = 0; ct < 4; ++ct)
                    acc[rt][ct] = __builtin_amdgcn_mfma_f32_16x16x32_bf16(
                        a[rt], b[ct], acc[rt][ct], 0, 0, 0);
            asm volatile("s_waitcnt vmcnt(0)" ::: "memory");
            __syncthreads();
            p ^= 1;
        }
        // selection: score = Ckey[col] - 2*dot; packed key = (bits&~31)|(kt<<2|ct)
        float ckv[4];
        #pragma unroll
        for (int ct = 0; ct < 4; ++ct)
            ckv[ct] = Ckey[kt * 256 + w * 64 + ct * 16 + lid];
        #pragma unroll
        for (int rt = 0; rt < 4; ++rt)
            #pragma unroll
            for (int ct = 0; ct < 4; ++ct) {
                unsigned meta = (unsigned)((kt << 2) | ct);
                #pragma unroll
                for (int g = 0; g < 4; ++g) {
                    float s = fmaf(-2.0f, acc[rt][ct][g], ckv[ct]);
                    unsigned key = (__float_as_uint(s) & 0xFFFFFFE0u) | meta;
                    unsigned o1 = t1[rt][g];
                    unsigned lo = key < o1 ? key : o1;
                    unsigned hi = key < o1 ? o1 : key;
                    t2[rt][g] = t2[rt][g] < hi ? t2[rt][g] : hi;
                    t1[rt][g] = lo;
                    acc[rt][ct][g] = 0.0f;
                }
            }
    }

    // ---- merge per-row 128 candidates -> top-8 ----
    __syncthreads();
    uint2* mb = reinterpret_cast<uint2*>(lds);          // [64 rows][64 pairs]
    #pragma unroll
    for (int rt = 0; rt < 4; ++rt)
        #pragma unroll
        for (int g = 0; g < 4; ++g) {
            int row = rt * 16 + kc * 4 + g;
            uint2 v; v.x = t1[rt][g]; v.y = t2[rt][g];
            mb[row * 64 + w * 16 + lid] = v;
        }
    __syncthreads();
    uint2* scr = reinterpret_cast<uint2*>(lds + 32768); // [64][4][8] (key, j)
    {
        int row = tid >> 2, q = tid & 3;
        const uint4* base = reinterpret_cast<const uint4*>(mb + (size_t)row * 64 + q * 16);
        unsigned prev = 0; int prevj = -1;
        for (int i = 0; i < 8; ++i) {
            unsigned cur = 0xFFFFFFFFu; int curj = 0x7FFFFFFF;
            for (int jj = 0; jj < 8; ++jj) {
                int j4 = (jj + tid) & 7;                // bank-spread rotation
                uint4 kv = base[j4];
                int j0 = q * 32 + j4 * 4;
                { unsigned kk=kv.x; int j=j0;   if (((kk>prev)||(kk==prev&&j>prevj)) && ((kk<cur)||(kk==cur&&j<curj))) {cur=kk;curj=j;} }
                { unsigned kk=kv.y; int j=j0+1; if (((kk>prev)||(kk==prev&&j>prevj)) && ((kk<cur)||(kk==cur&&j<curj))) {cur=kk;curj=j;} }
                { unsigned kk=kv.z; int j=j0+2; if (((kk>prev)||(kk==prev&&j>prevj)) && ((kk<cur)||(kk==cur&&j<curj))) {cur=kk;curj=j;} }
                { unsigned kk=kv.w; int j=j0+3; if (((kk>prev)||(kk==prev&&j>prevj)) && ((kk<cur)||(kk==cur&&j<curj))) {cur=kk;curj=j;} }
            }
            uint2 pr; pr.x = cur; pr.y = (unsigned)curj;
            scr[(row * 4 + q) * 8 + i] = pr;
            prev = cur; prevj = curj;
        }
    }
    __syncthreads();
    if (tid < 64) {
        const uint2* sr = scr + tid * 32;
        unsigned prev = 0; int prevj = -1;
        for (int i = 0; i < 8; ++i) {
            unsigned cur = 0xFFFFFFFFu; int curj = 0x7FFFFFFF;
            for (int m = 0; m < 32; ++m) {
                int mm = (m + tid) & 31;
                uint2 pr = sr[mm];
                unsigned kk = pr.x; int j = (int)pr.y;
                if (((kk>prev)||(kk==prev&&j>prevj)) && ((kk<cur)||(kk==cur&&j<curj))) {cur=kk;curj=j;}
            }
            prev = cur; prevj = curj;
            unsigned meta = cur & 31u;
            int kkk = (int)((meta >> 2) * 256) + ((curj >> 5) * 64)
                    + (int)((meta & 3) * 16) + ((curj >> 1) & 15);
            ck[(size_t)(nb + tid) * NCAND + i] = kkk;
        }
    }
}

// ---- refine: bitwise numpy-fp32 rescore of 8 candidates (1 thread per row,cand) ----
__global__ __launch_bounds__(256) void k_refine(const float* __restrict__ X,
                                                const float* __restrict__ E,
                                                const float* __restrict__ Cref,
                                                const int* __restrict__ ck,
                                                float* __restrict__ idx_out_f,
                                                int* __restrict__ ind) {
    __shared__ float Xl[RROWS][DD + 1];
    __shared__ uint2 res[RROWS][NCAND];
    const int tid = threadIdx.x;
    const int n0 = blockIdx.x * RROWS;
    const int b = n0 >> 10;
    const int hw0 = n0 & 1023;
    const float* xbase = X + (size_t)b * CHW + hw0;
    #pragma unroll
    for (int it = 0; it < RROWS; ++it) {
        int idx = tid + it * 256;
        int d = idx >> 5, r = idx & 31;
        Xl[r][d] = xbase[(size_t)d * HW + r];
    }
    __syncthreads();
    const int r = tid >> 3, c = tid & 7;
    const int n = n0 + r;
    float A;
    {
#pragma clang fp contract(off)
        float r0[8], r1[8];
        #pragma unroll
        for (int j = 0; j < 8; ++j) { float t = Xl[r][j];       r0[j] = t * t; }
        #pragma unroll
        for (int j = 0; j < 8; ++j) { float t = Xl[r][128 + j]; r1[j] = t * t; }
        for (int i = 8; i < 128; i += 8) {
            #pragma unroll
            for (int j = 0; j < 8; ++j) { float t = Xl[r][i + j];       r0[j] += t * t; }
            #pragma unroll
            for (int j = 0; j < 8; ++j) { float t = Xl[r][128 + i + j]; r1[j] += t * t; }
        }
        float lo = ((r0[0]+r0[1])+(r0[2]+r0[3]))+((r0[4]+r0[5])+(r0[6]+r0[7]));
        float hi = ((r1[0]+r1[1])+(r1[2]+r1[3]))+((r1[4]+r1[5])+(r1[6]+r1[7]));
        A = lo + hi;
    }
    int k = ck[(size_t)n * NCAND + c];
    const float* e = E + (size_t)k * DD;
    double m = 0.0;
    for (int d = 0; d < DD; d += 4) {
        m += (double)Xl[r][d]     * (double)e[d];
        m += (double)Xl[r][d + 1] * (double)e[d + 1];
        m += (double)Xl[r][d + 2] * (double)e[d + 2];
        m += (double)Xl[r][d + 3] * (double)e[d + 3];
    }
    float dist;
    {
#pragma clang fp contract(off)
        float M  = (float)m;
        float Bt = 2.0f * M;
        float T1 = A - Bt;
        dist = T1 + Cref[k];
    }
    uint2 pr; pr.x = __float_as_uint(dist); pr.y = (unsigned)k;  // dist > 0 always
    res[r][c] = pr;
    __syncthreads();
    if (tid < RROWS) {
        unsigned bd = 0xFFFFFFFFu; int bk = 0x7FFFFFFF;
        #pragma unroll
        for (int j = 0; j < NCAND; ++j) {
            uint2 p2 = res[tid][j];
            unsigned db = p2.x; int kk = (int)p2.y;
            if (db < bd || (db == bd && kk < bk)) { bd = db; bk = kk; }
        }
        ind[n0 + tid] = bk;
        idx_out_f[n0 + tid] = (float)bk;
    }
}

// ---- out = x + BETA*(E[ind] - x), NCHW, float4 over w ----
__global__ __launch_bounds__(256) void k_out(const float* __restrict__ X,
                                             const float* __restrict__ E,
                                             const int* __restrict__ ind,
                                             float* __restrict__ out) {
    int gid = blockIdx.x * 256 + threadIdx.x;
    int e0 = gid << 2;
    int hw = e0 & 1023;
    int d  = (e0 >> 10) & 255;
    int b  = e0 >> 18;
    int n0 = (b << 10) | hw;

    float4 x = *reinterpret_cast<const float4*>(X + e0);
    int4  iv = *reinterpret_cast<const int4*>(ind + n0);
    float q0 = E[(size_t)iv.x * DD + d];
    float q1 = E[(size_t)iv.y * DD + d];
    float q2 = E[(size_t)iv.z * DD + d];
    float q3 = E[(size_t)iv.w * DD + d];
    float4 r;
    r.x = x.x + BETA * (q0 - x.x);
    r.y = x.y + BETA * (q1 - x.y);
    r.z = x.z + BETA * (q2 - x.z);
    r.w = x.w + BETA * (q3 - x.w);
    *reinterpret_cast<float4*>(out + e0) = r;
}

extern "C" void kernel_launch(void* const* d_in, const int* in_sizes, int n_in,
                              void* d_out, int out_size, void* d_ws, size_t ws_size,
                              hipStream_t stream) {
    const float* lat = (const float*)d_in[0];      // (32,256,32,32) fp32
    const float* emb = (const float*)d_in[1];      // (2048,256) fp32
    float* out   = (float*)d_out;                  // 8388608 floats (output 0)
    float* idx_f = out + (size_t)BB * DD * HW;     // 32768 floats (output 1)

    // Large scratch lives in d_out's output-0 region (fully overwritten by
    // k_out at the end). d_ws holds only 144 KB.
    char*  ob   = (char*)d_out;
    uint4* XbfT = (uint4*)(ob);                    // 16 MB  (floats 0..4194303)
    uint4* EbfT = (uint4*)(ob + 16777216);         // 1 MB
    int*   ck   = (int*)(ob + 17825792);           // 1 MB   (ends at 18.8 MB < 32 MB)

    char* ws = (char*)d_ws;
    float* Ckey = (float*)(ws + 0);                // 8 KB
    float* Cref = (float*)(ws + 8192);             // 8 KB
    int*   ind  = (int*)(ws + 16384);              // 128 KB

    k_c      <<<KK / 256, 256, 0, stream>>>(emb, Cref, Ckey);
    k_ebf    <<<256, 256, 0, stream>>>(emb, EbfT);          // 65536 units
    k_xbf    <<<2048, 256, 0, stream>>>(lat, XbfT);
    k_screen <<<NN / 64, 256, 0, stream>>>(XbfT, EbfT, Ckey, ck);
    k_refine <<<NN / RROWS, 256, 0, stream>>>(lat, emb, Cref, ck, idx_f, ind);
    k_out    <<<(BB * DD * HW) / 4 / 256, 256, 0, stream>>>(lat, emb, ind, out);
}

// Round 6
// 183.625 us; speedup vs baseline: 4.1183x; 1.0156x over previous
//
#include <hip/hip_runtime.h>
#include <math.h>

#define BB 32
#define DD 256
#define KK 2048
#define HW 1024
#define CHW (DD*HW)
#define NN (BB*HW)         // 32768 rows
#define BETA 0.25f
#define NCAND 8
#define RROWS 32
#define BIAS 0.125f

typedef __attribute__((ext_vector_type(8))) short short8v;   // 8 bf16 (4 VGPR)
typedef __attribute__((ext_vector_type(4))) float f32x4;

typedef const __attribute__((address_space(1))) void gv_t;
typedef __attribute__((address_space(3))) void lv_t;

__device__ __forceinline__ void gl_lds16(const void* g, void* l) {
    // dest = wave-uniform base (+ lane*16 by HW); src = per-lane global addr
    __builtin_amdgcn_global_load_lds((gv_t*)g, (lv_t*)l, 16, 0, 0);
}

__device__ __forceinline__ unsigned bfr(float f) {           // fp32 -> bf16 RNE
    unsigned u = __float_as_uint(f);
    return (u + 0x7FFFu + ((u >> 16) & 1u)) >> 16;
}
__device__ __forceinline__ unsigned bfpack(float lo, float hi) {
    return bfr(lo) | (bfr(hi) << 16);
}

// ---- prep: blocks 0..255 convert E->bf16 tiled; blocks 256..263 compute C ----
// EbfT unit u = t*2048 + c*256 + kc*64 + code64   (t = 64-code tile)
__global__ __launch_bounds__(256) void k_prep(const float* __restrict__ E,
                                              uint4* __restrict__ EbfT,
                                              float* __restrict__ Cref,
                                              float* __restrict__ Ckey) {
    int bid = blockIdx.x;
    if (bid < 256) {
        int u = bid * 256 + threadIdx.x;                 // 0..65535
        int code = u & 63, kc = (u >> 6) & 3, c = (u >> 8) & 7, t = u >> 11;
        int k = t * 64 + code;
        const float* s = E + ((size_t)k * DD + c * 32 + kc * 8);
        float4 f0 = *reinterpret_cast<const float4*>(s);
        float4 f1 = *reinterpret_cast<const float4*>(s + 4);
        uint4 o;
        o.x = bfpack(f0.x, f0.y); o.y = bfpack(f0.z, f0.w);
        o.z = bfpack(f1.x, f1.y); o.w = bfpack(f1.z, f1.w);
        EbfT[u] = o;
    } else {
        int k = (bid - 256) * 256 + threadIdx.x;
        const float* e = E + (size_t)k * DD;
        float res;
        {
#pragma clang fp contract(off)
            float r0[8], r1[8];
            #pragma unroll
            for (int j = 0; j < 8; ++j) { float t = e[j];       r0[j] = t * t; }
            #pragma unroll
            for (int j = 0; j < 8; ++j) { float t = e[128 + j]; r1[j] = t * t; }
            for (int i = 8; i < 128; i += 8) {
                #pragma unroll
                for (int j = 0; j < 8; ++j) { float t = e[i + j];       r0[j] += t * t; }
                #pragma unroll
                for (int j = 0; j < 8; ++j) { float t = e[128 + i + j]; r1[j] += t * t; }
            }
            float lo = ((r0[0]+r0[1])+(r0[2]+r0[3]))+((r0[4]+r0[5])+(r0[6]+r0[7]));
            float hi = ((r1[0]+r1[1])+(r1[2]+r1[3]))+((r1[4]+r1[5])+(r1[6]+r1[7]));
            res = lo + hi;
        }
        Cref[k] = res;
        Ckey[k] = res + BIAS;
    }
}

// ---- X NCHW fp32 -> bf16 tiled: unit = rb*2048 + S*256 + kc*64 + row ----
__global__ __launch_bounds__(256) void k_xbf(const float* __restrict__ X,
                                             uint4* __restrict__ XbfT) {
    __shared__ float Tr[64][65];
    int tid = threadIdx.x;
    int bid = blockIdx.x;                  // 2048 blocks
    int b = bid >> 6, r = bid & 63;
    int hw0 = (r & 15) * 64, d0 = (r >> 4) * 64;
    const float* xb = X + (size_t)b * CHW + (size_t)d0 * HW + hw0;
    for (int j = 0; j < 16; ++j) {
        int idx = tid + j * 256;
        int d_l = idx >> 6, hw_l = idx & 63;
        Tr[hw_l][d_l] = xb[(size_t)d_l * HW + hw_l];   // coalesced 64-float rows
    }
    __syncthreads();
    int rb = b * 16 + (r & 15);
    for (int j = 0; j < 2; ++j) {
        int u = tid + j * 256;             // 0..511
        int hw_l = u & 63, c8 = u >> 6;    // 0..7
        int d = d0 + c8 * 8;
        const float* t = &Tr[hw_l][c8 * 8];
        uint4 o;
        o.x = bfpack(t[0], t[1]); o.y = bfpack(t[2], t[3]);
        o.z = bfpack(t[4], t[5]); o.w = bfpack(t[6], t[7]);
        int unit = rb * 2048 + (d >> 5) * 256 + ((d >> 3) & 3) * 64 + hw_l;
        XbfT[unit] = o;                    // coalesced 16B writes
    }
}

// ---- MFMA screen: X in registers, E streamed; per-row top-8 candidates ----
__global__ __launch_bounds__(256, 2) void k_screen(
        const uint4* __restrict__ XbfT, const uint4* __restrict__ EbfT,
        const float* __restrict__ Ckey, int* __restrict__ ck)
{
    __shared__ __align__(1024) char lds[81920];   // 2x32KB E dbuf + 16KB scr
    char* EsB = lds;

    const int tid = threadIdx.x;
    const int w = tid >> 6;
    const int lane = tid & 63;
    const int lid = lane & 15;
    const int kc = lane >> 4;
    const int nb = blockIdx.x * 64;

    // ---- A-fragments: 64 rows x 256 d, direct global->reg (128 VGPR) ----
    short8v a[8][4];
    {
        const uint4* xb = XbfT + (size_t)blockIdx.x * 2048 + kc * 64 + lid;
        #pragma unroll
        for (int c = 0; c < 8; ++c)
            #pragma unroll
            for (int rt = 0; rt < 4; ++rt) {
                uint4 v = xb[c * 256 + rt * 16];
                a[c][rt] = *reinterpret_cast<short8v*>(&v);
            }
    }
    // stage tile 0 -> buf0 (linear DMA)
    #pragma unroll
    for (int i = 0; i < 8; ++i)
        gl_lds16(EbfT + (w * 512 + i * 64 + lane), EsB + (w * 512 + i * 64) * 16);
    asm volatile("s_waitcnt vmcnt(0)" ::: "memory");
    __syncthreads();

    unsigned t1[4][4], t2[4][4], t3[4][4];
    #pragma unroll
    for (int i = 0; i < 4; ++i)
        #pragma unroll
        for (int j = 0; j < 4; ++j) {
            t1[i][j] = 0xFFFFFFFFu; t2[i][j] = 0xFFFFFFFFu; t3[i][j] = 0xFFFFFFFFu;
        }

    int p = 0;
    for (int t = 0; t < 32; ++t) {
        if (t < 31) {                      // prefetch next 64-code tile
            const uint4* src = EbfT + ((size_t)(t + 1) * 2048 + w * 512);
            char* dst = EsB + (p ^ 1) * 32768 + (w * 512) * 16;
            #pragma unroll
            for (int i = 0; i < 8; ++i)
                gl_lds16(src + i * 64 + lane, dst + i * 1024);
        }
        float ckv = Ckey[t * 64 + w * 16 + lid];
        f32x4 acc[4];
        #pragma unroll
        for (int rt = 0; rt < 4; ++rt) acc[rt] = (f32x4){0.f, 0.f, 0.f, 0.f};
        const short8v* Ev = reinterpret_cast<const short8v*>(EsB + p * 32768);
        #pragma unroll
        for (int c = 0; c < 8; ++c) {
            short8v b = Ev[(c * 4 + kc) * 64 + w * 16 + lid];
            #pragma unroll
            for (int rt = 0; rt < 4; ++rt)
                acc[rt] = __builtin_amdgcn_mfma_f32_16x16x32_bf16(
                    a[c][rt], b, acc[rt], 0, 0, 0);
        }
        // selection: key = (score bits & ~31) | tile ; per-(row) top-3 insert
        #pragma unroll
        for (int rt = 0; rt < 4; ++rt)
            #pragma unroll
            for (int g = 0; g < 4; ++g) {
                float s = fmaf(-2.0f, acc[rt][g], ckv);
                unsigned key = (__float_as_uint(s) & 0xFFFFFFE0u) | (unsigned)t;
                unsigned o1 = t1[rt][g];
                unsigned lo = key < o1 ? key : o1;
                unsigned hi = key < o1 ? o1 : key;
                t1[rt][g] = lo;
                unsigned o2 = t2[rt][g];
                unsigned m2 = hi < o2 ? hi : o2;
                unsigned h2 = hi < o2 ? o2 : hi;
                t2[rt][g] = m2;
                unsigned o3 = t3[rt][g];
                t3[rt][g] = h2 < o3 ? h2 : o3;
            }
        asm volatile("s_waitcnt vmcnt(0)" ::: "memory");
        __syncthreads();
        p ^= 1;
    }

    // ---- merge: 64 slots/row x 3 keys -> top-8 codes ----
    uint4* mb = reinterpret_cast<uint4*>(lds);          // [64 rows][64 slots]
    #pragma unroll
    for (int rt = 0; rt < 4; ++rt)
        #pragma unroll
        for (int g = 0; g < 4; ++g) {
            int row = rt * 16 + kc * 4 + g;
            uint4 v; v.x = t1[rt][g]; v.y = t2[rt][g]; v.z = t3[rt][g]; v.w = 0xFFFFFFFFu;
            mb[row * 64 + w * 16 + lid] = v;
        }
    __syncthreads();
    uint2* scr = reinterpret_cast<uint2*>(lds + 65536); // [64][4][8] (key, j)
    {
        int row = tid >> 2, q = tid & 3;
        uint4 kv[16]; int sl[16];
        #pragma unroll
        for (int s = 0; s < 16; ++s) {
            int slot = q * 16 + ((s + tid) & 15);       // bank-spread rotation
            kv[s] = mb[row * 64 + slot];
            sl[s] = slot;
        }
        unsigned prev = 0; int prevj = -1;
        for (int i = 0; i < 8; ++i) {
            unsigned cur = 0xFFFFFFFFu; int curj = 0x7FFFFFFF;
            #pragma unroll
            for (int s = 0; s < 16; ++s) {
                int j0 = sl[s] * 4;
                { unsigned k2=kv[s].x; int j=j0;   if ((k2>prev||(k2==prev&&j>prevj)) && (k2<cur||(k2==cur&&j<curj))) {cur=k2;curj=j;} }
                { unsigned k2=kv[s].y; int j=j0+1; if ((k2>prev||(k2==prev&&j>prevj)) && (k2<cur||(k2==cur&&j<curj))) {cur=k2;curj=j;} }
                { unsigned k2=kv[s].z; int j=j0+2; if ((k2>prev||(k2==prev&&j>prevj)) && (k2<cur||(k2==cur&&j<curj))) {cur=k2;curj=j;} }
            }
            uint2 pr; pr.x = cur; pr.y = (unsigned)curj;
            scr[(row * 4 + q) * 8 + i] = pr;
            prev = cur; prevj = curj;
        }
    }
    __syncthreads();
    if (tid < 64) {
        unsigned prev = 0; int prevj = -1;
        for (int i = 0; i < 8; ++i) {
            unsigned cur = 0xFFFFFFFFu; int curj = 0x7FFFFFFF;
            for (int m = 0; m < 32; ++m) {
                int mm = (m + tid) & 31;
                uint2 pr = scr[tid * 32 + mm];
                unsigned k2 = pr.x; int j = (int)pr.y;
                if ((k2>prev||(k2==prev&&j>prevj)) && (k2<cur||(k2==cur&&j<curj))) {cur=k2;curj=j;}
            }
            prev = cur; prevj = curj;
            int code = (int)(cur & 31u) * 64 + (curj >> 2);   // k = t*64 + slot
            ck[(size_t)(nb + tid) * NCAND + i] = code;
        }
    }
}

// ---- refine: bitwise numpy-fp32 rescore of 8 candidates (1 thread/(row,cand)) ----
__global__ __launch_bounds__(256) void k_refine(const float* __restrict__ X,
                                                const float* __restrict__ E,
                                                const float* __restrict__ Cref,
                                                const int* __restrict__ ck,
                                                float* __restrict__ idx_out_f,
                                                int* __restrict__ ind) {
    __shared__ float Xl[RROWS][DD + 4];
    __shared__ uint2 res[RROWS][NCAND];
    const int tid = threadIdx.x;
    const int n0 = blockIdx.x * RROWS;
    const int b = n0 >> 10;
    const int hw0 = n0 & 1023;
    const float* xbase = X + (size_t)b * CHW + hw0;
    #pragma unroll
    for (int it = 0; it < RROWS; ++it) {
        int idx = tid + it * 256;
        int d = idx >> 5, r = idx & 31;
        Xl[r][d] = xbase[(size_t)d * HW + r];
    }
    __syncthreads();
    const int r = tid >> 3, c = tid & 7;
    const int n = n0 + r;
    float A;
    {
#pragma clang fp contract(off)
        float r0[8], r1[8];
        #pragma unroll
        for (int j = 0; j < 8; ++j) { float t = Xl[r][j];       r0[j] = t * t; }
        #pragma unroll
        for (int j = 0; j < 8; ++j) { float t = Xl[r][128 + j]; r1[j] = t * t; }
        for (int i = 8; i < 128; i += 8) {
            #pragma unroll
            for (int j = 0; j < 8; ++j) { float t = Xl[r][i + j];       r0[j] += t * t; }
            #pragma unroll
            for (int j = 0; j < 8; ++j) { float t = Xl[r][128 + i + j]; r1[j] += t * t; }
        }
        float lo = ((r0[0]+r0[1])+(r0[2]+r0[3]))+((r0[4]+r0[5])+(r0[6]+r0[7]));
        float hi = ((r1[0]+r1[1])+(r1[2]+r1[3]))+((r1[4]+r1[5])+(r1[6]+r1[7]));
        A = lo + hi;
    }
    int k = ck[(size_t)n * NCAND + c];
    const float4* e4 = reinterpret_cast<const float4*>(E + (size_t)k * DD);
    const float4* x4 = reinterpret_cast<const float4*>(&Xl[r][0]);
    double m0 = 0.0, m1 = 0.0, m2 = 0.0, m3 = 0.0;   // f64 dot: order-free
    for (int i = 0; i < 64; i += 4) {
        float4 ev0 = e4[i],     xv0 = x4[i];
        float4 ev1 = e4[i + 1], xv1 = x4[i + 1];
        float4 ev2 = e4[i + 2], xv2 = x4[i + 2];
        float4 ev3 = e4[i + 3], xv3 = x4[i + 3];
        m0 += (double)ev0.x*xv0.x + (double)ev0.y*xv0.y + (double)ev0.z*xv0.z + (double)ev0.w*xv0.w;
        m1 += (double)ev1.x*xv1.x + (double)ev1.y*xv1.y + (double)ev1.z*xv1.z + (double)ev1.w*xv1.w;
        m2 += (double)ev2.x*xv2.x + (double)ev2.y*xv2.y + (double)ev2.z*xv2.z + (double)ev2.w*xv2.w;
        m3 += (double)ev3.x*xv3.x + (double)ev3.y*xv3.y + (double)ev3.z*xv3.z + (double)ev3.w*xv3.w;
    }
    double m = (m0 + m1) + (m2 + m3);
    float dist;
    {
#pragma clang fp contract(off)
        float M  = (float)m;
        float Bt = 2.0f * M;
        float T1 = A - Bt;
        dist = T1 + Cref[k];
    }
    uint2 pr; pr.x = __float_as_uint(dist); pr.y = (unsigned)k;  // dist > 0 always
    res[r][c] = pr;
    __syncthreads();
    if (tid < RROWS) {
        unsigned bd = 0xFFFFFFFFu; int bk = 0x7FFFFFFF;
        #pragma unroll
        for (int j = 0; j < NCAND; ++j) {
            uint2 p2 = res[tid][j];
            unsigned db = p2.x; int kk = (int)p2.y;
            if (db < bd || (db == bd && kk < bk)) { bd = db; bk = kk; }
        }
        ind[n0 + tid] = bk;
        idx_out_f[n0 + tid] = (float)bk;
    }
}

// ---- out = x + BETA*(E[ind] - x), NCHW, float4 over w ----
__global__ __launch_bounds__(256) void k_out(const float* __restrict__ X,
                                             const float* __restrict__ E,
                                             const int* __restrict__ ind,
                                             float* __restrict__ out) {
    int gid = blockIdx.x * 256 + threadIdx.x;
    int e0 = gid << 2;
    int hw = e0 & 1023;
    int d  = (e0 >> 10) & 255;
    int b  = e0 >> 18;
    int n0 = (b << 10) | hw;

    float4 x = *reinterpret_cast<const float4*>(X + e0);
    int4  iv = *reinterpret_cast<const int4*>(ind + n0);
    float q0 = E[(size_t)iv.x * DD + d];
    float q1 = E[(size_t)iv.y * DD + d];
    float q2 = E[(size_t)iv.z * DD + d];
    float q3 = E[(size_t)iv.w * DD + d];
    float4 r;
    r.x = x.x + BETA * (q0 - x.x);
    r.y = x.y + BETA * (q1 - x.y);
    r.z = x.z + BETA * (q2 - x.z);
    r.w = x.w + BETA * (q3 - x.w);
    *reinterpret_cast<float4*>(out + e0) = r;
}

extern "C" void kernel_launch(void* const* d_in, const int* in_sizes, int n_in,
                              void* d_out, int out_size, void* d_ws, size_t ws_size,
                              hipStream_t stream) {
    const float* lat = (const float*)d_in[0];      // (32,256,32,32) fp32
    const float* emb = (const float*)d_in[1];      // (2048,256) fp32
    float* out   = (float*)d_out;                  // 8388608 floats (output 0)
    float* idx_f = out + (size_t)BB * DD * HW;     // 32768 floats (output 1)

    // Large scratch lives in d_out's output-0 region (fully overwritten by
    // k_out at the end; all readers precede k_out). d_ws holds 144 KB.
    char*  ob   = (char*)d_out;
    uint4* XbfT = (uint4*)(ob);                    // 16 MB
    uint4* EbfT = (uint4*)(ob + 16777216);         // 1 MB
    int*   ck   = (int*)(ob + 17825792);           // 1 MB (ends 18.9 MB < 32 MB)

    char* ws = (char*)d_ws;
    float* Ckey = (float*)(ws + 0);                // 8 KB
    float* Cref = (float*)(ws + 8192);             // 8 KB
    int*   ind  = (int*)(ws + 16384);              // 128 KB

    k_prep   <<<264, 256, 0, stream>>>(emb, EbfT, Cref, Ckey);
    k_xbf    <<<2048, 256, 0, stream>>>(lat, XbfT);
    k_screen <<<NN / 64, 256, 0, stream>>>(XbfT, EbfT, Ckey, ck);
    k_refine <<<NN / RROWS, 256, 0, stream>>>(lat, emb, Cref, ck, idx_f, ind);
    k_out    <<<(BB * DD * HW) / 4 / 256, 256, 0, stream>>>(lat, emb, ind, out);
}